// Round 11
// baseline (319.366 us; speedup 1.0000x reference)
//
#include <hip/hip_runtime.h>

using f32x4  = __attribute__((ext_vector_type(4))) float;
using bf16x8 = __attribute__((ext_vector_type(8))) short;
using u32x4  = __attribute__((ext_vector_type(4))) unsigned int;
using u32x2  = __attribute__((ext_vector_type(2))) unsigned int;
typedef unsigned short u16;

__device__ __forceinline__ u16 f2bf(float f) {
  unsigned u = __float_as_uint(f);
  unsigned r = (u + 0x7FFFu + ((u >> 16) & 1u)) >> 16;
  return (u16)r;
}

// ---------------- Kernel 1: 1x1 convs (+ z=3: conv3x3 weight cvt -> lane-linear MFMA tiles)
__global__ void __launch_bounds__(256) k1_conv1x1(
    const float* __restrict__ x, const float* __restrict__ wB, const float* __restrict__ bB,
    const float* __restrict__ wC, const float* __restrict__ bC,
    const float* __restrict__ wD, const float* __restrict__ bD,
    u16* __restrict__ featBb, u16* __restrict__ featCb, u16* __restrict__ featD,
    const float* __restrict__ cw, u16* __restrict__ wb) {
  const int t = threadIdx.x;
  const int b = blockIdx.y;
  const int z = blockIdx.z;
  if (z == 3) {
    int gid = (b * 16 + blockIdx.x) * 256 + t;
#pragma unroll
    for (int k = 0; k < 3; ++k) {
      int F = gid + k * 32768;
      if (F < 73728) {
        int j = F & 7, lane = (F >> 3) & 63, T = F >> 9;
        int tap = T >> 4, g = (T >> 1) & 7, kc = T & 1;
        int l16 = lane & 15, quad = lane >> 4;
        int oc = g * 16 + l16, ic = kc * 32 + quad * 8 + j;
        wb[F] = f2bf(cw[(oc * 64 + ic) * 9 + tap]);
      }
    }
    return;
  }
  __shared__ float W[2048];
  __shared__ float Bias[32];
  const int n = blockIdx.x * 256 + t;
  if (z == 0) {
    for (int i = t; i < 512; i += 256) W[i] = wB[i];
    for (int i = t; i < 512; i += 256) W[512 + i] = wC[i];
    if (t < 8) Bias[t] = bB[t];
    if (t >= 8 && t < 16) Bias[t] = bC[t - 8];
  } else {
    const float* wsrc = wD + (z - 1) * 2048;
    for (int i = t; i < 2048; i += 256) W[i] = wsrc[i];
    if (t < 32) Bias[t] = bD[(z - 1) * 32 + t];
  }
  __syncthreads();
  float xv[64];
#pragma unroll
  for (int c = 0; c < 64; ++c) xv[c] = x[((b * 64 + c) << 12) + n];
  if (z == 0) {
    float o[16];
#pragma unroll
    for (int k = 0; k < 16; ++k) {
      f32x4 s = {0.f, 0.f, 0.f, 0.f};
#pragma unroll
      for (int cq = 0; cq < 16; ++cq) {
        f32x4 wv = *(const f32x4*)&W[k * 64 + cq * 4];
        f32x4 xq = {xv[cq * 4], xv[cq * 4 + 1], xv[cq * 4 + 2], xv[cq * 4 + 3]};
        s += wv * xq;
      }
      o[k] = Bias[k] + s[0] + s[1] + s[2] + s[3];
    }
    int base = ((b << 12) + n) * 8;
    u32x4 pb, pc;
#pragma unroll
    for (int i = 0; i < 4; ++i) {
      pb[i] = (unsigned)f2bf(o[2 * i]) | ((unsigned)f2bf(o[2 * i + 1]) << 16);
      pc[i] = (unsigned)f2bf(o[8 + 2 * i]) | ((unsigned)f2bf(o[8 + 2 * i + 1]) << 16);
    }
    *(u32x4*)&featBb[base] = pb;
    *(u32x4*)&featCb[base] = pc;
  } else {
#pragma unroll 4
    for (int k = 0; k < 32; ++k) {
      f32x4 s = {0.f, 0.f, 0.f, 0.f};
#pragma unroll
      for (int cq = 0; cq < 16; ++cq) {
        f32x4 wv = *(const f32x4*)&W[k * 64 + cq * 4];
        f32x4 xq = {xv[cq * 4], xv[cq * 4 + 1], xv[cq * 4 + 2], xv[cq * 4 + 3]};
        s += wv * xq;
      }
      float val = Bias[k] + s[0] + s[1] + s[2] + s[3];
      featD[((b * 64 + (z - 1) * 32 + k) << 12) + n] = f2bf(val);
    }
  }
}

// ---------------- Kernel 2: PAM partial attention, split-m z=4, 4 n-tiles per wave,
// Ps halved to 2 in-flight slots -> LDS 37 KB -> 4 blocks/CU (was 2) for pipe overlap.
__global__ void __launch_bounds__(256, 4) k2_pam_part(
    const u16* __restrict__ fBb, const u16* __restrict__ fCb, const u16* __restrict__ fD,
    u16* __restrict__ numPart, float* __restrict__ denPart) {
  __shared__ u16 Kf[128 * 8];          // 2 KB
  __shared__ u16 Df[64 * 132];         // 16.5 KB
  __shared__ u16 Ps4[4][2][16 * 72];   // 18 KB: [wave][jslot][n16 x m64+pad]
  const int t = threadIdx.x, b = blockIdx.y, z = blockIdx.z;
  const int w = t >> 6, lane = t & 63, quad = lane >> 4, l16 = lane & 15;
  const int nb = blockIdx.x * 256 + w * 64;
  u16* myPs = &Ps4[w][0][0];

  bf16x8 bq[4];
#pragma unroll
  for (int j = 0; j < 4; ++j) {
    bq[j] = *(const bf16x8*)&fBb[(((b << 12) + nb + j * 16 + l16) << 3)];
    if (quad != 0) bq[j] = (bf16x8)(short)0;
  }

  f32x4 acc[4][4];
#pragma unroll
  for (int ct = 0; ct < 4; ++ct)
#pragma unroll
    for (int j = 0; j < 4; ++j) acc[ct][j] = (f32x4){0.f, 0.f, 0.f, 0.f};
  float denp[4] = {0.f, 0.f, 0.f, 0.f};
  const int mz = z << 10;

  for (int ch = 0; ch < 8; ++ch) {
    const int m0 = mz + (ch << 7);
    __syncthreads();
    if (t < 128) *(u32x4*)&Kf[t * 8] = *(const u32x4*)&fCb[(((b << 12) + m0 + t) << 3)];
#pragma unroll
    for (int h = 0; h < 4; ++h) {
      int idx = h * 256 + t;
      int r = idx >> 4, mo = (idx & 15) << 3;
      *(u32x4*)&Df[r * 132 + mo] = *(const u32x4*)&fD[((b * 64 + r) << 12) + m0 + mo];
    }
    __syncthreads();
#pragma unroll
    for (int sub = 0; sub < 2; ++sub) {
      const int ms = sub * 64;
#pragma unroll
      for (int jp = 0; jp < 2; ++jp) {
        // ---- S = K.Q^T for the 2 n-tiles of this pair
#pragma unroll
        for (int mt = 0; mt < 4; ++mt) {
          bf16x8 af = *(const bf16x8*)&Kf[(ms + mt * 16 + l16) * 8];
#pragma unroll
          for (int jj = 0; jj < 2; ++jj) {
            const int j = jp * 2 + jj;
            f32x4 zero = {0.f, 0.f, 0.f, 0.f};
            f32x4 s = __builtin_amdgcn_mfma_f32_16x16x32_bf16(af, bq[j], zero, 0, 0, 0);
            float e0 = __expf(s[0]), e1 = __expf(s[1]), e2 = __expf(s[2]), e3 = __expf(s[3]);
            denp[j] += (e0 + e1) + (e2 + e3);
            u32x2 pk;
            pk[0] = __builtin_amdgcn_perm(__float_as_uint(e1), __float_as_uint(e0), 0x07060302u);
            pk[1] = __builtin_amdgcn_perm(__float_as_uint(e3), __float_as_uint(e2), 0x07060302u);
            *(u32x2*)&myPs[jj * 1152 + l16 * 72 + mt * 16 + quad * 4] = pk;
          }
        }
        // ---- PV for the pair (Ps is wave-private: in-wave LDS order suffices, no barrier)
#pragma unroll
        for (int kc = 0; kc < 2; ++kc) {
          bf16x8 bv0 = *(const bf16x8*)&myPs[0 * 1152 + l16 * 72 + kc * 32 + quad * 8];
          bf16x8 bv1 = *(const bf16x8*)&myPs[1 * 1152 + l16 * 72 + kc * 32 + quad * 8];
#pragma unroll
          for (int ct = 0; ct < 4; ++ct) {
            bf16x8 av = *(const bf16x8*)&Df[(ct * 16 + l16) * 132 + ms + kc * 32 + quad * 8];
            acc[ct][jp * 2]     = __builtin_amdgcn_mfma_f32_16x16x32_bf16(av, bv0, acc[ct][jp * 2], 0, 0, 0);
            acc[ct][jp * 2 + 1] = __builtin_amdgcn_mfma_f32_16x16x32_bf16(av, bv1, acc[ct][jp * 2 + 1], 0, 0, 0);
          }
        }
      }
    }
  }
#pragma unroll
  for (int j = 0; j < 4; ++j) {
    denp[j] += __shfl_xor(denp[j], 16);
    denp[j] += __shfl_xor(denp[j], 32);
  }
  const int zb = z * 8 + b;
#pragma unroll
  for (int ct = 0; ct < 4; ++ct)
#pragma unroll
    for (int j = 0; j < 4; ++j)
#pragma unroll
      for (int r = 0; r < 4; ++r) {
        int c = ct * 16 + quad * 4 + r;
        numPart[((zb * 64 + c) << 12) + nb + j * 16 + l16] = (u16)(__float_as_uint(acc[ct][j][r]) >> 16);
      }
  if (quad == 0)
#pragma unroll
    for (int j = 0; j < 4; ++j) denPart[(zb << 12) + nb + j * 16 + l16] = denp[j];
}

// ---------------- Kernel 3: reduce PAM partials -> x1 (global + LDS), then CAM gram partials
__global__ void __launch_bounds__(256) k3_gram(
    const u16* __restrict__ numPart, const float* __restrict__ denPart,
    const float* __restrict__ x, const float* __restrict__ alpha,
    float* __restrict__ x1, float* __restrict__ attPart) {
  __shared__ float X[64 * 132];
  __shared__ float Dinv[128];
  const int t = threadIdx.x, b = blockIdx.y, cx = blockIdx.x;
  const int n0 = cx * 128;
  if (t < 128) {
    float den = 0.f;
#pragma unroll
    for (int z = 0; z < 4; ++z) den += denPart[(((z * 8 + b) << 12)) + n0 + t];
    Dinv[t] = alpha[0] / den;
  }
  __syncthreads();
  for (int idx = t; idx < 4096; idx += 256) {
    int row = idx >> 6, cp = (idx & 63) * 2;
    int gi = ((b * 64 + row) << 12) + n0 + cp;
    float num0 = 0.f, num1 = 0.f;
#pragma unroll
    for (int z = 0; z < 4; ++z) {
      unsigned v = *(const unsigned*)&numPart[(((z * 8 + b) * 64 + row) << 12) + n0 + cp];
      num0 += __uint_as_float(v << 16);
      num1 += __uint_as_float(v & 0xFFFF0000u);
    }
    float v0 = num0 * Dinv[cp] + x[gi];
    float v1 = num1 * Dinv[cp + 1] + x[gi + 1];
    X[row * 132 + cp] = v0;
    X[row * 132 + cp + 1] = v1;
    x1[gi] = v0;
    x1[gi + 1] = v1;
  }
  __syncthreads();
  const int cg = t >> 4, dg = t & 15;
  f32x4 acc[4][4];
#pragma unroll
  for (int i = 0; i < 4; ++i)
#pragma unroll
    for (int k = 0; k < 4; ++k) acc[i][k] = (f32x4){0.f, 0.f, 0.f, 0.f};
  for (int nq0 = 0; nq0 < 32; ++nq0) {
    int nq = (nq0 + dg) & 31;
    f32x4 a[4], bb[4];
#pragma unroll
    for (int i = 0; i < 4; ++i) a[i] = *(const f32x4*)&X[(cg * 4 + i) * 132 + nq * 4];
#pragma unroll
    for (int k = 0; k < 4; ++k) bb[k] = *(const f32x4*)&X[(dg * 4 + k) * 132 + nq * 4];
#pragma unroll
    for (int i = 0; i < 4; ++i)
#pragma unroll
      for (int k = 0; k < 4; ++k) acc[i][k] += a[i] * bb[k];
  }
#pragma unroll
  for (int i = 0; i < 4; ++i)
#pragma unroll
    for (int k = 0; k < 4; ++k) {
      f32x4 s = acc[i][k];
      attPart[((b * 32 + cx) * 64 + cg * 4 + i) * 64 + dg * 4 + k] = s[0] + s[1] + s[2] + s[3];
    }
}

// ---------------- Kernel 4: CAM softmax (min-form), one wave per c-row. grid (16, 8)
__global__ void __launch_bounds__(256) k4_softmax(const float* __restrict__ attPart, float* __restrict__ attP) {
  const int b = blockIdx.y, t = threadIdx.x;
  const int c = (blockIdx.x << 2) + (t >> 6), d = t & 63;
  float v = 0.f;
  for (int p = 0; p < 32; ++p) v += attPart[((b * 32 + p) * 64 + c) * 64 + d];
  float mn = v;
#pragma unroll
  for (int off = 1; off < 64; off <<= 1) mn = fminf(mn, __shfl_xor(mn, off));
  float e = __expf(mn - v);
  float sum = e;
#pragma unroll
  for (int off = 1; off < 64; off <<= 1) sum += __shfl_xor(sum, off);
  attP[(b * 64 + c) * 64 + d] = e / sum;
}

// ---------------- Kernel 5: x2 = beta*(attP @ x1) + x1, bf16 NHWC. grid (16,8) x 256
__global__ void __launch_bounds__(256) k5_apply(
    const float* __restrict__ attP, const float* __restrict__ x1,
    const float* __restrict__ beta, u16* __restrict__ x2b) {
  __shared__ float A[64 * 68];
  const int t = threadIdx.x, b = blockIdx.y;
  for (int idx = t; idx < 4096; idx += 256) A[(idx >> 6) * 68 + (idx & 63)] = attP[(b << 12) + idx];
  __syncthreads();
  const int n = blockIdx.x * 256 + t;
  float xv[64];
#pragma unroll
  for (int d = 0; d < 64; ++d) xv[d] = x1[((b * 64 + d) << 12) + n];
  const float bv = beta[0];
  u16* orow = x2b + (((size_t)(b << 12) + n) << 6);
#pragma unroll 2
  for (int cg = 0; cg < 8; ++cg) {
    unsigned pk[4];
#pragma unroll
    for (int ci = 0; ci < 8; ++ci) {
      int c = cg * 8 + ci;
      f32x4 s = {0.f, 0.f, 0.f, 0.f};
#pragma unroll
      for (int dq = 0; dq < 16; ++dq) {
        f32x4 avv = *(const f32x4*)&A[c * 68 + dq * 4];
        f32x4 xq = {xv[dq * 4], xv[dq * 4 + 1], xv[dq * 4 + 2], xv[dq * 4 + 3]};
        s += avv * xq;
      }
      float fe = s[0] + s[1] + s[2] + s[3];
      float val = bv * fe + xv[c];
      unsigned h = f2bf(val);
      if ((ci & 1) == 0) pk[ci >> 1] = h;
      else pk[ci >> 1] |= h << 16;
    }
    *(u32x4*)&orow[cg * 8] = (u32x4){pk[0], pk[1], pk[2], pk[3]};
  }
}

// ---------------- Kernel 6: conv3x3 bf16 MFMA, lane-linear weight tiles
__global__ void __launch_bounds__(256) k6_mfma(const u16* __restrict__ x2b, const u16* __restrict__ wb,
                                               float* __restrict__ y) {
  __shared__ u16 Xl[3 * 66 * 72];
  const int t = threadIdx.x, b = blockIdx.y, h = blockIdx.x;
  for (int idx = t; idx < 3 * 66 * 8; idx += 256) {
    int r = idx / 528;
    int rem = idx - r * 528;
    int c = rem >> 3, icq = rem & 7;
    int gy = h - 1 + r, gx = c - 1;
    u32x4 v = {0u, 0u, 0u, 0u};
    if (gy >= 0 && gy < 64 && gx >= 0 && gx < 64)
      v = *(const u32x4*)&x2b[(((size_t)(b << 6 | gy) << 6) + gx) * 64 + icq * 8];
    *(u32x4*)&Xl[(r * 66 + c) * 72 + icq * 8] = v;
  }
  __syncthreads();
  const int w = t >> 6, lane = t & 63, quad = lane >> 4, l16 = lane & 15;
  const int mBase = (w & 1) * 64;
  const int og = (w & 1) * 4;
  const int nBase = (w >> 1) * 32;
  f32x4 acc[4][2];
#pragma unroll
  for (int ot = 0; ot < 4; ++ot)
#pragma unroll
    for (int nt = 0; nt < 2; ++nt) acc[ot][nt] = (f32x4){0.f, 0.f, 0.f, 0.f};
#pragma unroll 3
  for (int tap = 0; tap < 9; ++tap) {
    const int dy = tap / 3, dx = tap - dy * 3;
    bf16x8 af[4][2];
#pragma unroll
    for (int ot = 0; ot < 4; ++ot)
#pragma unroll
      for (int kc = 0; kc < 2; ++kc)
        af[ot][kc] = *(const bf16x8*)&wb[((((tap * 8 + og + ot) * 2 + kc) << 6) + lane) << 3];
#pragma unroll
    for (int nt = 0; nt < 2; ++nt) {
      const int prow = dy * 66 + nBase + nt * 16 + l16 + dx;
#pragma unroll
      for (int kc = 0; kc < 2; ++kc) {
        bf16x8 bv = *(const bf16x8*)&Xl[prow * 72 + kc * 32 + quad * 8];
#pragma unroll
        for (int ot = 0; ot < 4; ++ot)
          acc[ot][nt] = __builtin_amdgcn_mfma_f32_16x16x32_bf16(af[ot][kc], bv, acc[ot][nt], 0, 0, 0);
      }
    }
  }
#pragma unroll
  for (int ot = 0; ot < 4; ++ot)
#pragma unroll
    for (int nt = 0; nt < 2; ++nt)
#pragma unroll
      for (int r = 0; r < 4; ++r) {
        int oc = mBase + ot * 16 + quad * 4 + r;
        int pix = nBase + nt * 16 + l16;
        y[((b * 128 + oc) << 12) + (h << 6) + pix] = acc[ot][nt][r];
      }
}

// ---------------- Kernel 7: BN partial stats. grid (128 ch, 4)
__global__ void __launch_bounds__(256) k7_part(const float* __restrict__ y, float* __restrict__ pstats) {
  const int ch = blockIdx.x, q = blockIdx.y, t = threadIdx.x;
  float s = 0.f, ss = 0.f;
#pragma unroll
  for (int bb = 0; bb < 2; ++bb) {
    const float* p = y + (((q * 2 + bb) * 128 + ch) << 12);
#pragma unroll
    for (int i = 0; i < 16; ++i) { float v = p[i * 256 + t]; s += v; ss += v * v; }
  }
#pragma unroll
  for (int off = 1; off < 64; off <<= 1) { s += __shfl_xor(s, off); ss += __shfl_xor(ss, off); }
  __shared__ float rs[4], rss[4];
  if ((t & 63) == 0) { rs[t >> 6] = s; rss[t >> 6] = ss; }
  __syncthreads();
  if (t == 0) {
    pstats[ch * 8 + q * 2]     = rs[0] + rs[1] + rs[2] + rs[3];
    pstats[ch * 8 + q * 2 + 1] = rss[0] + rss[1] + rss[2] + rss[3];
  }
}

// ---------------- Kernel 8: BN finalize + ReLU + maxpool(2,2, hpad=1)
__global__ void __launch_bounds__(256) k8_pool(const float* __restrict__ y, const float* __restrict__ pstats,
                                               const float* __restrict__ gamma, const float* __restrict__ bbeta,
                                               float* __restrict__ out) {
  const int bc = blockIdx.x;
  const int ch = bc & 127;
  float S = 0.f, SS = 0.f;
#pragma unroll
  for (int q = 0; q < 4; ++q) { S += pstats[ch * 8 + q * 2]; SS += pstats[ch * 8 + q * 2 + 1]; }
  const float mean = S * (1.f / 32768.f);
  const float var = SS * (1.f / 32768.f) - mean * mean;
  const float sc = gamma[ch] * rsqrtf(var + 1e-5f);
  const float sh = bbeta[ch] - mean * sc;
  const float* p = y + (bc << 12);
  float* op = out + bc * (33 * 32);
  for (int i = threadIdx.x; i < 33 * 32; i += 256) {
    int oh = i >> 5, ow = i & 31;
    int r0 = 2 * oh - 1, r1 = 2 * oh;
    float m = 0.f;
    if (r0 >= 0) {
      m = fmaxf(m, p[r0 * 64 + 2 * ow] * sc + sh);
      m = fmaxf(m, p[r0 * 64 + 2 * ow + 1] * sc + sh);
    }
    if (r1 <= 63) {
      m = fmaxf(m, p[r1 * 64 + 2 * ow] * sc + sh);
      m = fmaxf(m, p[r1 * 64 + 2 * ow + 1] * sc + sh);
    }
    op[i] = m;
  }
}

extern "C" void kernel_launch(void* const* d_in, const int* in_sizes, int n_in,
                              void* d_out, int out_size, void* d_ws, size_t ws_size,
                              hipStream_t stream) {
  const float* x      = (const float*)d_in[0];
  const float* wB     = (const float*)d_in[1];
  const float* bB     = (const float*)d_in[2];
  const float* wC     = (const float*)d_in[3];
  const float* bC     = (const float*)d_in[4];
  const float* wD     = (const float*)d_in[5];
  const float* bD     = (const float*)d_in[6];
  const float* alpha  = (const float*)d_in[7];
  const float* beta   = (const float*)d_in[8];
  const float* cw     = (const float*)d_in[9];
  const float* gamma  = (const float*)d_in[11];
  const float* bnbeta = (const float*)d_in[12];

  // Workspace overlays (35.3 MB):
  //  [0,4M):      featBb/featCb/fDb [k1..k2p]  then x2b [k5..k6]
  //  [5M,13M):    x1 [k3..k5]
  //  [13M,29.8M): numPart [k2p..k3]  then y [k6..k8]
  //  [29.0M+..]:  denPart, attPart, attP, wb, pstats
  char* ws = (char*)d_ws;
  u16*   featBb  = (u16*)  (ws + 0);          // 512 KB
  u16*   featCb  = (u16*)  (ws + 524288);     // 512 KB
  u16*   fDb     = (u16*)  (ws + 1048576);    // 4 MB
  u16*   x2b     = (u16*)  (ws + 0);          // 4 MB (bf16 NHWC) — over feat*
  float* x1      = (float*)(ws + 5242880);    // 8 MB
  u16*   numPart = (u16*)  (ws + 13631488);   // 16 MB
  float* y       = (float*)(ws + 13631488);   // 16 MB — over numPart
  float* denPart = (float*)(ws + 30408704);   // 512 KB
  float* attPart = (float*)(ws + 30932992);   // 4 MB
  float* attP    = (float*)(ws + 35127296);   // 128 KB
  u16*   wb      = (u16*)  (ws + 35258368);   // 144 KB
  float* pstats  = (float*)(ws + 35405824);   // 4 KB
  float* outp    = (float*)d_out;

  k1_conv1x1<<<dim3(16, 8, 4), 256, 0, stream>>>(x, wB, bB, wC, bC, wD, bD, featBb, featCb, fDb, cw, wb);
  k2_pam_part<<<dim3(16, 8, 4), 256, 0, stream>>>(featBb, featCb, fDb, numPart, denPart);
  k3_gram<<<dim3(32, 8), 256, 0, stream>>>(numPart, denPart, x, alpha, x1, attPart);
  k4_softmax<<<dim3(16, 8), 256, 0, stream>>>(attPart, attP);
  k5_apply<<<dim3(16, 8), 256, 0, stream>>>(attP, x1, beta, x2b);
  k6_mfma<<<dim3(64, 8), 256, 0, stream>>>(x2b, wb, y);
  k7_part<<<dim3(128, 4), 256, 0, stream>>>(y, pstats);
  k8_pool<<<dim3(1024), 256, 0, stream>>>(y, pstats, gamma, bnbeta, outp);
}

// Round 12
// 216.108 us; speedup vs baseline: 1.4778x; 1.4778x over previous
//
#include <hip/hip_runtime.h>

using f32x4  = __attribute__((ext_vector_type(4))) float;
using bf16x8 = __attribute__((ext_vector_type(8))) short;
using u32x4  = __attribute__((ext_vector_type(4))) unsigned int;
using u32x2  = __attribute__((ext_vector_type(2))) unsigned int;
typedef unsigned short u16;

__device__ __forceinline__ u16 f2bf(float f) {
  unsigned u = __float_as_uint(f);
  unsigned r = (u + 0x7FFFu + ((u >> 16) & 1u)) >> 16;
  return (u16)r;
}

// ---------------- Kernel 1: 1x1 convs (+ z=3: conv3x3 weight cvt -> lane-linear MFMA tiles)
__global__ void __launch_bounds__(256) k1_conv1x1(
    const float* __restrict__ x, const float* __restrict__ wB, const float* __restrict__ bB,
    const float* __restrict__ wC, const float* __restrict__ bC,
    const float* __restrict__ wD, const float* __restrict__ bD,
    u16* __restrict__ featBb, u16* __restrict__ featCb, u16* __restrict__ featD,
    const float* __restrict__ cw, u16* __restrict__ wb) {
  const int t = threadIdx.x;
  const int b = blockIdx.y;
  const int z = blockIdx.z;
  if (z == 3) {
    int gid = (b * 16 + blockIdx.x) * 256 + t;
#pragma unroll
    for (int k = 0; k < 3; ++k) {
      int F = gid + k * 32768;
      if (F < 73728) {
        int j = F & 7, lane = (F >> 3) & 63, T = F >> 9;
        int tap = T >> 4, g = (T >> 1) & 7, kc = T & 1;
        int l16 = lane & 15, quad = lane >> 4;
        int oc = g * 16 + l16, ic = kc * 32 + quad * 8 + j;
        wb[F] = f2bf(cw[(oc * 64 + ic) * 9 + tap]);
      }
    }
    return;
  }
  __shared__ float W[2048];
  __shared__ float Bias[32];
  const int n = blockIdx.x * 256 + t;
  if (z == 0) {
    for (int i = t; i < 512; i += 256) W[i] = wB[i];
    for (int i = t; i < 512; i += 256) W[512 + i] = wC[i];
    if (t < 8) Bias[t] = bB[t];
    if (t >= 8 && t < 16) Bias[t] = bC[t - 8];
  } else {
    const float* wsrc = wD + (z - 1) * 2048;
    for (int i = t; i < 2048; i += 256) W[i] = wsrc[i];
    if (t < 32) Bias[t] = bD[(z - 1) * 32 + t];
  }
  __syncthreads();
  float xv[64];
#pragma unroll
  for (int c = 0; c < 64; ++c) xv[c] = x[((b * 64 + c) << 12) + n];
  if (z == 0) {
    float o[16];
#pragma unroll
    for (int k = 0; k < 16; ++k) {
      f32x4 s = {0.f, 0.f, 0.f, 0.f};
#pragma unroll
      for (int cq = 0; cq < 16; ++cq) {
        f32x4 wv = *(const f32x4*)&W[k * 64 + cq * 4];
        f32x4 xq = {xv[cq * 4], xv[cq * 4 + 1], xv[cq * 4 + 2], xv[cq * 4 + 3]};
        s += wv * xq;
      }
      o[k] = Bias[k] + s[0] + s[1] + s[2] + s[3];
    }
    int base = ((b << 12) + n) * 8;
    u32x4 pb, pc;
#pragma unroll
    for (int i = 0; i < 4; ++i) {
      pb[i] = (unsigned)f2bf(o[2 * i]) | ((unsigned)f2bf(o[2 * i + 1]) << 16);
      pc[i] = (unsigned)f2bf(o[8 + 2 * i]) | ((unsigned)f2bf(o[8 + 2 * i + 1]) << 16);
    }
    *(u32x4*)&featBb[base] = pb;
    *(u32x4*)&featCb[base] = pc;
  } else {
#pragma unroll 4
    for (int k = 0; k < 32; ++k) {
      f32x4 s = {0.f, 0.f, 0.f, 0.f};
#pragma unroll
      for (int cq = 0; cq < 16; ++cq) {
        f32x4 wv = *(const f32x4*)&W[k * 64 + cq * 4];
        f32x4 xq = {xv[cq * 4], xv[cq * 4 + 1], xv[cq * 4 + 2], xv[cq * 4 + 3]};
        s += wv * xq;
      }
      float val = Bias[k] + s[0] + s[1] + s[2] + s[3];
      featD[((b * 64 + (z - 1) * 32 + k) << 12) + n] = f2bf(val);
    }
  }
}

// ---------------- Kernel 2: PAM partial attention, split-m z=4, 4 n-tiles per wave.
// Ps = 2 in-flight slots -> LDS 37 KB. NO min-waves launch_bounds arg: R11 showed
// __launch_bounds__(256,4) forces VGPR=64 -> 400+MB scratch spill. Compiler naturally
// hits 128 VGPR (R9) = exactly 4 waves/SIMD, so 37 KB LDS gives 4 blocks/CU.
__global__ void __launch_bounds__(256) k2_pam_part(
    const u16* __restrict__ fBb, const u16* __restrict__ fCb, const u16* __restrict__ fD,
    u16* __restrict__ numPart, float* __restrict__ denPart) {
  __shared__ u16 Kf[128 * 8];          // 2 KB
  __shared__ u16 Df[64 * 132];         // 16.5 KB
  __shared__ u16 Ps4[4][2][16 * 72];   // 18 KB: [wave][jslot][n16 x m64+pad]
  const int t = threadIdx.x, b = blockIdx.y, z = blockIdx.z;
  const int w = t >> 6, lane = t & 63, quad = lane >> 4, l16 = lane & 15;
  const int nb = blockIdx.x * 256 + w * 64;
  u16* myPs = &Ps4[w][0][0];

  bf16x8 bq[4];
#pragma unroll
  for (int j = 0; j < 4; ++j) {
    bq[j] = *(const bf16x8*)&fBb[(((b << 12) + nb + j * 16 + l16) << 3)];
    if (quad != 0) bq[j] = (bf16x8)(short)0;
  }

  f32x4 acc[4][4];
#pragma unroll
  for (int ct = 0; ct < 4; ++ct)
#pragma unroll
    for (int j = 0; j < 4; ++j) acc[ct][j] = (f32x4){0.f, 0.f, 0.f, 0.f};
  float denp[4] = {0.f, 0.f, 0.f, 0.f};
  const int mz = z << 10;

  for (int ch = 0; ch < 8; ++ch) {
    const int m0 = mz + (ch << 7);
    __syncthreads();
    if (t < 128) *(u32x4*)&Kf[t * 8] = *(const u32x4*)&fCb[(((b << 12) + m0 + t) << 3)];
#pragma unroll
    for (int h = 0; h < 4; ++h) {
      int idx = h * 256 + t;
      int r = idx >> 4, mo = (idx & 15) << 3;
      *(u32x4*)&Df[r * 132 + mo] = *(const u32x4*)&fD[((b * 64 + r) << 12) + m0 + mo];
    }
    __syncthreads();
#pragma unroll
    for (int sub = 0; sub < 2; ++sub) {
      const int ms = sub * 64;
#pragma unroll
      for (int jp = 0; jp < 2; ++jp) {
        // ---- S = K.Q^T for the 2 n-tiles of this pair
#pragma unroll
        for (int mt = 0; mt < 4; ++mt) {
          bf16x8 af = *(const bf16x8*)&Kf[(ms + mt * 16 + l16) * 8];
#pragma unroll
          for (int jj = 0; jj < 2; ++jj) {
            const int j = jp * 2 + jj;
            f32x4 zero = {0.f, 0.f, 0.f, 0.f};
            f32x4 s = __builtin_amdgcn_mfma_f32_16x16x32_bf16(af, bq[j], zero, 0, 0, 0);
            float e0 = __expf(s[0]), e1 = __expf(s[1]), e2 = __expf(s[2]), e3 = __expf(s[3]);
            denp[j] += (e0 + e1) + (e2 + e3);
            u32x2 pk;
            pk[0] = __builtin_amdgcn_perm(__float_as_uint(e1), __float_as_uint(e0), 0x07060302u);
            pk[1] = __builtin_amdgcn_perm(__float_as_uint(e3), __float_as_uint(e2), 0x07060302u);
            *(u32x2*)&myPs[jj * 1152 + l16 * 72 + mt * 16 + quad * 4] = pk;
          }
        }
        // ---- PV for the pair (Ps is wave-private: in-wave LDS order suffices, no barrier)
#pragma unroll
        for (int kc = 0; kc < 2; ++kc) {
          bf16x8 bv0 = *(const bf16x8*)&myPs[0 * 1152 + l16 * 72 + kc * 32 + quad * 8];
          bf16x8 bv1 = *(const bf16x8*)&myPs[1 * 1152 + l16 * 72 + kc * 32 + quad * 8];
#pragma unroll
          for (int ct = 0; ct < 4; ++ct) {
            bf16x8 av = *(const bf16x8*)&Df[(ct * 16 + l16) * 132 + ms + kc * 32 + quad * 8];
            acc[ct][jp * 2]     = __builtin_amdgcn_mfma_f32_16x16x32_bf16(av, bv0, acc[ct][jp * 2], 0, 0, 0);
            acc[ct][jp * 2 + 1] = __builtin_amdgcn_mfma_f32_16x16x32_bf16(av, bv1, acc[ct][jp * 2 + 1], 0, 0, 0);
          }
        }
      }
    }
  }
#pragma unroll
  for (int j = 0; j < 4; ++j) {
    denp[j] += __shfl_xor(denp[j], 16);
    denp[j] += __shfl_xor(denp[j], 32);
  }
  const int zb = z * 8 + b;
#pragma unroll
  for (int ct = 0; ct < 4; ++ct)
#pragma unroll
    for (int j = 0; j < 4; ++j)
#pragma unroll
      for (int r = 0; r < 4; ++r) {
        int c = ct * 16 + quad * 4 + r;
        numPart[((zb * 64 + c) << 12) + nb + j * 16 + l16] = (u16)(__float_as_uint(acc[ct][j][r]) >> 16);
      }
  if (quad == 0)
#pragma unroll
    for (int j = 0; j < 4; ++j) denPart[(zb << 12) + nb + j * 16 + l16] = denp[j];
}

// ---------------- Kernel 3: reduce PAM partials -> x1 (global + LDS), then CAM gram partials
__global__ void __launch_bounds__(256) k3_gram(
    const u16* __restrict__ numPart, const float* __restrict__ denPart,
    const float* __restrict__ x, const float* __restrict__ alpha,
    float* __restrict__ x1, float* __restrict__ attPart) {
  __shared__ float X[64 * 132];
  __shared__ float Dinv[128];
  const int t = threadIdx.x, b = blockIdx.y, cx = blockIdx.x;
  const int n0 = cx * 128;
  if (t < 128) {
    float den = 0.f;
#pragma unroll
    for (int z = 0; z < 4; ++z) den += denPart[(((z * 8 + b) << 12)) + n0 + t];
    Dinv[t] = alpha[0] / den;
  }
  __syncthreads();
  for (int idx = t; idx < 4096; idx += 256) {
    int row = idx >> 6, cp = (idx & 63) * 2;
    int gi = ((b * 64 + row) << 12) + n0 + cp;
    float num0 = 0.f, num1 = 0.f;
#pragma unroll
    for (int z = 0; z < 4; ++z) {
      unsigned v = *(const unsigned*)&numPart[(((z * 8 + b) * 64 + row) << 12) + n0 + cp];
      num0 += __uint_as_float(v << 16);
      num1 += __uint_as_float(v & 0xFFFF0000u);
    }
    float v0 = num0 * Dinv[cp] + x[gi];
    float v1 = num1 * Dinv[cp + 1] + x[gi + 1];
    X[row * 132 + cp] = v0;
    X[row * 132 + cp + 1] = v1;
    x1[gi] = v0;
    x1[gi + 1] = v1;
  }
  __syncthreads();
  const int cg = t >> 4, dg = t & 15;
  f32x4 acc[4][4];
#pragma unroll
  for (int i = 0; i < 4; ++i)
#pragma unroll
    for (int k = 0; k < 4; ++k) acc[i][k] = (f32x4){0.f, 0.f, 0.f, 0.f};
  for (int nq0 = 0; nq0 < 32; ++nq0) {
    int nq = (nq0 + dg) & 31;
    f32x4 a[4], bb[4];
#pragma unroll
    for (int i = 0; i < 4; ++i) a[i] = *(const f32x4*)&X[(cg * 4 + i) * 132 + nq * 4];
#pragma unroll
    for (int k = 0; k < 4; ++k) bb[k] = *(const f32x4*)&X[(dg * 4 + k) * 132 + nq * 4];
#pragma unroll
    for (int i = 0; i < 4; ++i)
#pragma unroll
      for (int k = 0; k < 4; ++k) acc[i][k] += a[i] * bb[k];
  }
#pragma unroll
  for (int i = 0; i < 4; ++i)
#pragma unroll
    for (int k = 0; k < 4; ++k) {
      f32x4 s = acc[i][k];
      attPart[((b * 32 + cx) * 64 + cg * 4 + i) * 64 + dg * 4 + k] = s[0] + s[1] + s[2] + s[3];
    }
}

// ---------------- Kernel 4: CAM softmax (min-form), one wave per c-row. grid (16, 8)
__global__ void __launch_bounds__(256) k4_softmax(const float* __restrict__ attPart, float* __restrict__ attP) {
  const int b = blockIdx.y, t = threadIdx.x;
  const int c = (blockIdx.x << 2) + (t >> 6), d = t & 63;
  float v = 0.f;
  for (int p = 0; p < 32; ++p) v += attPart[((b * 32 + p) * 64 + c) * 64 + d];
  float mn = v;
#pragma unroll
  for (int off = 1; off < 64; off <<= 1) mn = fminf(mn, __shfl_xor(mn, off));
  float e = __expf(mn - v);
  float sum = e;
#pragma unroll
  for (int off = 1; off < 64; off <<= 1) sum += __shfl_xor(sum, off);
  attP[(b * 64 + c) * 64 + d] = e / sum;
}

// ---------------- Kernel 5: x2 = beta*(attP @ x1) + x1, bf16 NHWC. grid (16,8) x 256
__global__ void __launch_bounds__(256) k5_apply(
    const float* __restrict__ attP, const float* __restrict__ x1,
    const float* __restrict__ beta, u16* __restrict__ x2b) {
  __shared__ float A[64 * 68];
  const int t = threadIdx.x, b = blockIdx.y;
  for (int idx = t; idx < 4096; idx += 256) A[(idx >> 6) * 68 + (idx & 63)] = attP[(b << 12) + idx];
  __syncthreads();
  const int n = blockIdx.x * 256 + t;
  float xv[64];
#pragma unroll
  for (int d = 0; d < 64; ++d) xv[d] = x1[((b * 64 + d) << 12) + n];
  const float bv = beta[0];
  u16* orow = x2b + (((size_t)(b << 12) + n) << 6);
#pragma unroll 2
  for (int cg = 0; cg < 8; ++cg) {
    unsigned pk[4];
#pragma unroll
    for (int ci = 0; ci < 8; ++ci) {
      int c = cg * 8 + ci;
      f32x4 s = {0.f, 0.f, 0.f, 0.f};
#pragma unroll
      for (int dq = 0; dq < 16; ++dq) {
        f32x4 avv = *(const f32x4*)&A[c * 68 + dq * 4];
        f32x4 xq = {xv[dq * 4], xv[dq * 4 + 1], xv[dq * 4 + 2], xv[dq * 4 + 3]};
        s += avv * xq;
      }
      float fe = s[0] + s[1] + s[2] + s[3];
      float val = bv * fe + xv[c];
      unsigned h = f2bf(val);
      if ((ci & 1) == 0) pk[ci >> 1] = h;
      else pk[ci >> 1] |= h << 16;
    }
    *(u32x4*)&orow[cg * 8] = (u32x4){pk[0], pk[1], pk[2], pk[3]};
  }
}

// ---------------- Kernel 6: conv3x3 bf16 MFMA, lane-linear weight tiles
__global__ void __launch_bounds__(256) k6_mfma(const u16* __restrict__ x2b, const u16* __restrict__ wb,
                                               float* __restrict__ y) {
  __shared__ u16 Xl[3 * 66 * 72];
  const int t = threadIdx.x, b = blockIdx.y, h = blockIdx.x;
  for (int idx = t; idx < 3 * 66 * 8; idx += 256) {
    int r = idx / 528;
    int rem = idx - r * 528;
    int c = rem >> 3, icq = rem & 7;
    int gy = h - 1 + r, gx = c - 1;
    u32x4 v = {0u, 0u, 0u, 0u};
    if (gy >= 0 && gy < 64 && gx >= 0 && gx < 64)
      v = *(const u32x4*)&x2b[(((size_t)(b << 6 | gy) << 6) + gx) * 64 + icq * 8];
    *(u32x4*)&Xl[(r * 66 + c) * 72 + icq * 8] = v;
  }
  __syncthreads();
  const int w = t >> 6, lane = t & 63, quad = lane >> 4, l16 = lane & 15;
  const int mBase = (w & 1) * 64;
  const int og = (w & 1) * 4;
  const int nBase = (w >> 1) * 32;
  f32x4 acc[4][2];
#pragma unroll
  for (int ot = 0; ot < 4; ++ot)
#pragma unroll
    for (int nt = 0; nt < 2; ++nt) acc[ot][nt] = (f32x4){0.f, 0.f, 0.f, 0.f};
#pragma unroll 3
  for (int tap = 0; tap < 9; ++tap) {
    const int dy = tap / 3, dx = tap - dy * 3;
    bf16x8 af[4][2];
#pragma unroll
    for (int ot = 0; ot < 4; ++ot)
#pragma unroll
      for (int kc = 0; kc < 2; ++kc)
        af[ot][kc] = *(const bf16x8*)&wb[((((tap * 8 + og + ot) * 2 + kc) << 6) + lane) << 3];
#pragma unroll
    for (int nt = 0; nt < 2; ++nt) {
      const int prow = dy * 66 + nBase + nt * 16 + l16 + dx;
#pragma unroll
      for (int kc = 0; kc < 2; ++kc) {
        bf16x8 bv = *(const bf16x8*)&Xl[prow * 72 + kc * 32 + quad * 8];
#pragma unroll
        for (int ot = 0; ot < 4; ++ot)
          acc[ot][nt] = __builtin_amdgcn_mfma_f32_16x16x32_bf16(af[ot][kc], bv, acc[ot][nt], 0, 0, 0);
      }
    }
  }
#pragma unroll
  for (int ot = 0; ot < 4; ++ot)
#pragma unroll
    for (int nt = 0; nt < 2; ++nt)
#pragma unroll
      for (int r = 0; r < 4; ++r) {
        int oc = mBase + ot * 16 + quad * 4 + r;
        int pix = nBase + nt * 16 + l16;
        y[((b * 128 + oc) << 12) + (h << 6) + pix] = acc[ot][nt][r];
      }
}

// ---------------- Kernel 7: BN partial stats. grid (128 ch, 4)
__global__ void __launch_bounds__(256) k7_part(const float* __restrict__ y, float* __restrict__ pstats) {
  const int ch = blockIdx.x, q = blockIdx.y, t = threadIdx.x;
  float s = 0.f, ss = 0.f;
#pragma unroll
  for (int bb = 0; bb < 2; ++bb) {
    const float* p = y + (((q * 2 + bb) * 128 + ch) << 12);
#pragma unroll
    for (int i = 0; i < 16; ++i) { float v = p[i * 256 + t]; s += v; ss += v * v; }
  }
#pragma unroll
  for (int off = 1; off < 64; off <<= 1) { s += __shfl_xor(s, off); ss += __shfl_xor(ss, off); }
  __shared__ float rs[4], rss[4];
  if ((t & 63) == 0) { rs[t >> 6] = s; rss[t >> 6] = ss; }
  __syncthreads();
  if (t == 0) {
    pstats[ch * 8 + q * 2]     = rs[0] + rs[1] + rs[2] + rs[3];
    pstats[ch * 8 + q * 2 + 1] = rss[0] + rss[1] + rss[2] + rss[3];
  }
}

// ---------------- Kernel 8: BN finalize + ReLU + maxpool(2,2, hpad=1)
__global__ void __launch_bounds__(256) k8_pool(const float* __restrict__ y, const float* __restrict__ pstats,
                                               const float* __restrict__ gamma, const float* __restrict__ bbeta,
                                               float* __restrict__ out) {
  const int bc = blockIdx.x;
  const int ch = bc & 127;
  float S = 0.f, SS = 0.f;
#pragma unroll
  for (int q = 0; q < 4; ++q) { S += pstats[ch * 8 + q * 2]; SS += pstats[ch * 8 + q * 2 + 1]; }
  const float mean = S * (1.f / 32768.f);
  const float var = SS * (1.f / 32768.f) - mean * mean;
  const float sc = gamma[ch] * rsqrtf(var + 1e-5f);
  const float sh = bbeta[ch] - mean * sc;
  const float* p = y + (bc << 12);
  float* op = out + bc * (33 * 32);
  for (int i = threadIdx.x; i < 33 * 32; i += 256) {
    int oh = i >> 5, ow = i & 31;
    int r0 = 2 * oh - 1, r1 = 2 * oh;
    float m = 0.f;
    if (r0 >= 0) {
      m = fmaxf(m, p[r0 * 64 + 2 * ow] * sc + sh);
      m = fmaxf(m, p[r0 * 64 + 2 * ow + 1] * sc + sh);
    }
    if (r1 <= 63) {
      m = fmaxf(m, p[r1 * 64 + 2 * ow] * sc + sh);
      m = fmaxf(m, p[r1 * 64 + 2 * ow + 1] * sc + sh);
    }
    op[i] = m;
  }
}

extern "C" void kernel_launch(void* const* d_in, const int* in_sizes, int n_in,
                              void* d_out, int out_size, void* d_ws, size_t ws_size,
                              hipStream_t stream) {
  const float* x      = (const float*)d_in[0];
  const float* wB     = (const float*)d_in[1];
  const float* bB     = (const float*)d_in[2];
  const float* wC     = (const float*)d_in[3];
  const float* bC     = (const float*)d_in[4];
  const float* wD     = (const float*)d_in[5];
  const float* bD     = (const float*)d_in[6];
  const float* alpha  = (const float*)d_in[7];
  const float* beta   = (const float*)d_in[8];
  const float* cw     = (const float*)d_in[9];
  const float* gamma  = (const float*)d_in[11];
  const float* bnbeta = (const float*)d_in[12];

  // Workspace overlays (35.3 MB):
  //  [0,4M):      featBb/featCb/fDb [k1..k2p]  then x2b [k5..k6]
  //  [5M,13M):    x1 [k3..k5]
  //  [13M,29.8M): numPart [k2p..k3]  then y [k6..k8]
  //  [29.0M+..]:  denPart, attPart, attP, wb, pstats
  char* ws = (char*)d_ws;
  u16*   featBb  = (u16*)  (ws + 0);          // 512 KB
  u16*   featCb  = (u16*)  (ws + 524288);     // 512 KB
  u16*   fDb     = (u16*)  (ws + 1048576);    // 4 MB
  u16*   x2b     = (u16*)  (ws + 0);          // 4 MB (bf16 NHWC) — over feat*
  float* x1      = (float*)(ws + 5242880);    // 8 MB
  u16*   numPart = (u16*)  (ws + 13631488);   // 16 MB
  float* y       = (float*)(ws + 13631488);   // 16 MB — over numPart
  float* denPart = (float*)(ws + 30408704);   // 512 KB
  float* attPart = (float*)(ws + 30932992);   // 4 MB
  float* attP    = (float*)(ws + 35127296);   // 128 KB
  u16*   wb      = (u16*)  (ws + 35258368);   // 144 KB
  float* pstats  = (float*)(ws + 35405824);   // 4 KB
  float* outp    = (float*)d_out;

  k1_conv1x1<<<dim3(16, 8, 4), 256, 0, stream>>>(x, wB, bB, wC, bC, wD, bD, featBb, featCb, fDb, cw, wb);
  k2_pam_part<<<dim3(16, 8, 4), 256, 0, stream>>>(featBb, featCb, fDb, numPart, denPart);
  k3_gram<<<dim3(32, 8), 256, 0, stream>>>(numPart, denPart, x, alpha, x1, attPart);
  k4_softmax<<<dim3(16, 8), 256, 0, stream>>>(attPart, attP);
  k5_apply<<<dim3(16, 8), 256, 0, stream>>>(attP, x1, beta, x2b);
  k6_mfma<<<dim3(64, 8), 256, 0, stream>>>(x2b, wb, y);
  k7_part<<<dim3(128, 4), 256, 0, stream>>>(y, pstats);
  k8_pool<<<dim3(1024), 256, 0, stream>>>(y, pstats, gamma, bnbeta, outp);
}